// Round 13
// baseline (454.293 us; speedup 1.0000x reference)
//
#include <hip/hip_runtime.h>
#include <hip/hip_bf16.h>

#define N_NODES 20000
#define E_EDGES 320000
#define F_INN   64
#define HID     128
#define HEADS   2
#define HC      (HEADS * HID)   // 256
#define G_GR    64
#define MIDD    32
#define EPSV    1e-5f
#define NBUK    79              // ceil(20000/256); bucket = node >> 8

#define CDIV(a, b) (((a) + (b) - 1) / (b))

typedef __attribute__((ext_vector_type(8))) short          bf16x8;  // MFMA A/B frag
typedef __attribute__((ext_vector_type(4))) float          f32x4;   // MFMA C/D frag
typedef __attribute__((ext_vector_type(8))) unsigned short u16x8;

// ---------- bf16 helpers (RNE) ----------
__device__ inline float bf2f(unsigned short u) { return __uint_as_float((unsigned)u << 16); }
__device__ inline unsigned short f2bf(float f) {
    unsigned u = __float_as_uint(f);
    unsigned r = u + 0x7FFFu + ((u >> 16) & 1u);
    return (unsigned short)(r >> 16);
}

// ================= CSR construction (3 CSRs, bucket-granular two-pass) ========
struct Csr3 {
    const int* key[3];
    const int* other[3];   // payload source for y=0,1; y=2 stores edge id
    int* btot;      // [3*NBUK] bucket totals (zeroed)
    int* bstart;    // [3*(NBUK+1)] bucket starts
    int* bcur;      // [3*NBUK] bucket cursors
    int* rowptr[3]; // [N+1] (written by bucketB)
    int* out[3];    // [E] payload (final, CSR order)
    int2* tmp;      // [3*E] (key,payload) bucket-partitioned
};

__global__ __launch_bounds__(256) void k_bhist(Csr3 c) {
    __shared__ int hist[NBUK];
    const int y = blockIdx.y;
    const int chunk0 = blockIdx.x * 4096;
    const int t = threadIdx.x;
    for (int i = t; i < NBUK; i += 256) hist[i] = 0;
    __syncthreads();
#pragma unroll
    for (int i = 0; i < 16; i++) {
        int e = chunk0 + (i << 8) + t;
        if (e < E_EDGES) atomicAdd(&hist[c.key[y][e] >> 8], 1);
    }
    __syncthreads();
    for (int i = t; i < NBUK; i += 256)
        if (hist[i] > 0) atomicAdd(&c.btot[y * NBUK + i], hist[i]);
}

__global__ void k_bscan(Csr3 c) {
    __shared__ int sh[3 * NBUK];
    int t = threadIdx.x;
    for (int i = t; i < 3 * NBUK; i += 256) sh[i] = c.btot[i];
    __syncthreads();
    if (t < 3) {
        int run = 0;
        int* bs = c.bstart + t * (NBUK + 1);
        for (int b = 0; b < NBUK; b++) {
            bs[b] = run;
            c.bcur[t * NBUK + b] = run;
            run += sh[t * NBUK + b];
        }
        bs[NBUK] = run;
    }
}

__global__ __launch_bounds__(256) void k_bucketA(Csr3 c) {
    __shared__ int hist[NBUK], base[NBUK], off[NBUK];
    const int y = blockIdx.y;
    const int chunk0 = blockIdx.x * 4096;
    const int t = threadIdx.x;
    for (int i = t; i < NBUK; i += 256) { hist[i] = 0; off[i] = 0; }
    __syncthreads();
    int keys[16], vals[16], bks[16];
#pragma unroll
    for (int i = 0; i < 16; i++) {
        int e = chunk0 + (i << 8) + t;
        bool ok = (e < E_EDGES);
        int k = ok ? c.key[y][e] : 0;
        keys[i] = k;
        vals[i] = ok ? ((y == 2) ? e : c.other[y][e]) : 0;
        bks[i] = ok ? (k >> 8) : -1;
        if (ok) atomicAdd(&hist[k >> 8], 1);
    }
    __syncthreads();
    if (t < NBUK && hist[t] > 0) base[t] = atomicAdd(&c.bcur[y * NBUK + t], hist[t]);
    __syncthreads();
    int2* ty = c.tmp + (size_t)y * E_EDGES;
#pragma unroll
    for (int i = 0; i < 16; i++) {
        int b = bks[i];
        if (b >= 0) {
            int o = atomicAdd(&off[b], 1);
            ty[base[b] + o] = make_int2(keys[i], vals[i]);
        }
    }
}

__global__ __launch_bounds__(256) void k_bucketB(Csr3 c) {
    __shared__ int cnt[256], lbase[256], run[256];
    const int y = blockIdx.y;
    const int b = blockIdx.x;
    const int nbase = b << 8;
    const int t = threadIdx.x;
    cnt[t] = 0; run[t] = 0;
    __syncthreads();
    const int bs = c.bstart[y * (NBUK + 1) + b];
    const int be = c.bstart[y * (NBUK + 1) + b + 1];
    const int2* ty = c.tmp + (size_t)y * E_EDGES;
    for (int i = bs + t; i < be; i += 256)
        atomicAdd(&cnt[ty[i].x - nbase], 1);
    __syncthreads();
    int v = cnt[t];
    lbase[t] = v;
    __syncthreads();
    for (int off = 1; off < 256; off <<= 1) {
        int u = (t >= off) ? lbase[t - off] : 0;
        __syncthreads();
        lbase[t] += u;
        __syncthreads();
    }
    int excl = lbase[t] - v;
    __syncthreads();
    lbase[t] = excl;
    __syncthreads();
    int n = nbase + t;
    if (n < N_NODES) c.rowptr[y][n] = bs + excl;
    if (b == NBUK - 1 && t == 0) c.rowptr[y][N_NODES] = E_EDGES;
    int* outy = c.out[y];
    for (int i = bs + t; i < be; i += 256) {
        int2 kv = ty[i];
        int k = kv.x - nbase;
        int o = atomicAdd(&run[k], 1);
        outy[bs + lbase[k] + o] = kv.y;
    }
}

// ===== GANConv0 aggregation: z[n] = bf16(x[n] + sum x[srcs]) , fp32 input, unroll-4 =====
__global__ __launch_bounds__(256) void k_gather_f32(const float4* __restrict__ x,
                                                    const int* __restrict__ rowptr,
                                                    const int* __restrict__ srcs,
                                                    unsigned short* __restrict__ z) {
    int gid = blockIdx.x * blockDim.x + threadIdx.x;
    int n = gid >> 4;
    if (n >= N_NODES) return;
    int q = gid & 15;
    float4 acc = x[((size_t)n << 4) + q];
    float4 a1 = make_float4(0.f, 0.f, 0.f, 0.f), a2 = a1, a3 = a1;
    int p = rowptr[n], p1 = rowptr[n + 1];
    for (; p + 4 <= p1; p += 4) {
        float4 v0 = x[((size_t)srcs[p + 0] << 4) + q];
        float4 v1 = x[((size_t)srcs[p + 1] << 4) + q];
        float4 v2 = x[((size_t)srcs[p + 2] << 4) + q];
        float4 v3 = x[((size_t)srcs[p + 3] << 4) + q];
        acc.x += v0.x; acc.y += v0.y; acc.z += v0.z; acc.w += v0.w;
        a1.x += v1.x; a1.y += v1.y; a1.z += v1.z; a1.w += v1.w;
        a2.x += v2.x; a2.y += v2.y; a2.z += v2.z; a2.w += v2.w;
        a3.x += v3.x; a3.y += v3.y; a3.z += v3.z; a3.w += v3.w;
    }
    for (; p < p1; p++) {
        float4 v = x[((size_t)srcs[p] << 4) + q];
        acc.x += v.x; acc.y += v.y; acc.z += v.z; acc.w += v.w;
    }
    acc.x += a1.x + a2.x + a3.x; acc.y += a1.y + a2.y + a3.y;
    acc.z += a1.z + a2.z + a3.z; acc.w += a1.w + a2.w + a3.w;
    ushort4 o;
    o.x = f2bf(acc.x); o.y = f2bf(acc.y); o.z = f2bf(acc.z); o.w = f2bf(acc.w);
    *(ushort4*)&z[((size_t)n << 6) + (q << 2)] = o;
}

// ===== GANConv1 aggregation with fused BN+relu on load, unroll-4 =====
__global__ __launch_bounds__(256) void k_gather_bn(const u16x8* __restrict__ raw,
                                                   const int* __restrict__ rowptr,
                                                   const int* __restrict__ srcs,
                                                   const float* __restrict__ bn_sums,
                                                   const float* __restrict__ g,
                                                   const float* __restrict__ b,
                                                   u16x8* __restrict__ z) {
    int gid = blockIdx.x * blockDim.x + threadIdx.x;
    int n = gid >> 4;
    if (n >= N_NODES) return;
    int q = gid & 15;
    float sc[8], sh[8];
#pragma unroll
    for (int i = 0; i < 8; i++) {
        int c = (q << 3) + i;
        float mean = bn_sums[c] / N_NODES;
        float istd = rsqrtf(bn_sums[HID + c] / N_NODES - mean * mean + EPSV);
        float s = istd * g[c];
        sc[i] = s;
        sh[i] = b[c] - mean * s;
    }
    u16x8 u0 = raw[((size_t)n << 4) + q];
    float acc[8];
#pragma unroll
    for (int i = 0; i < 8; i++) acc[i] = fmaxf(bf2f(u0[i]) * sc[i] + sh[i], 0.f);
    int p = rowptr[n], p1 = rowptr[n + 1];
    for (; p + 4 <= p1; p += 4) {
        u16x8 v0 = raw[((size_t)srcs[p + 0] << 4) + q];
        u16x8 v1 = raw[((size_t)srcs[p + 1] << 4) + q];
        u16x8 v2 = raw[((size_t)srcs[p + 2] << 4) + q];
        u16x8 v3 = raw[((size_t)srcs[p + 3] << 4) + q];
#pragma unroll
        for (int i = 0; i < 8; i++) {
            acc[i] += fmaxf(bf2f(v0[i]) * sc[i] + sh[i], 0.f)
                    + fmaxf(bf2f(v1[i]) * sc[i] + sh[i], 0.f)
                    + fmaxf(bf2f(v2[i]) * sc[i] + sh[i], 0.f)
                    + fmaxf(bf2f(v3[i]) * sc[i] + sh[i], 0.f);
        }
    }
    for (; p < p1; p++) {
        u16x8 v = raw[((size_t)srcs[p] << 4) + q];
#pragma unroll
        for (int i = 0; i < 8; i++) acc[i] += fmaxf(bf2f(v[i]) * sc[i] + sh[i], 0.f);
    }
    u16x8 o;
#pragma unroll
    for (int i = 0; i < 8; i++) o[i] = f2bf(acc[i]);
    z[((size_t)n << 4) + q] = o;
}

// ===== weight prep: Wt[n][k] = bf16(W[k][n]) for 8 weights in one launch =====
struct WtJob  { const float* src; unsigned short* dst; int K; int N; };
struct WtJobs { WtJob j[8]; };
__global__ void k_wt_cast(WtJobs jobs) {
    WtJob jb = jobs.j[blockIdx.y];
    int total = jb.K * jb.N;
    for (int i = blockIdx.x * blockDim.x + threadIdx.x; i < total; i += gridDim.x * blockDim.x) {
        int nn = i / jb.K, kk = i - nn * jb.K;
        jb.dst[i] = f2bf(jb.src[(size_t)kk * jb.N + nn]);
    }
}

// ===== MFMA bf16 GEMM: C[M,N] = A'[M,K] @ Wt[N,K]^T + bias; bf16 out =====
template <int STATS, int BNA, int TM, int BIAS2>
__global__ __launch_bounds__(256) void k_mfma_gemm(const unsigned short* __restrict__ A,
                                                   const unsigned short* __restrict__ Wt,
                                                   const float* __restrict__ biasL,
                                                   const float* __restrict__ biasR,
                                                   unsigned short* __restrict__ Cout,
                                                   int M, int K, int N,
                                                   float* __restrict__ stats_sums,
                                                   const float* __restrict__ bn_sums,
                                                   const float* __restrict__ bn_g,
                                                   const float* __restrict__ bn_b) {
    constexpr int BNF = (TM == 128) ? 4 : 2;
    __shared__ unsigned short As[TM][40];
    __shared__ unsigned short Bs[128][40];
    __shared__ float s_scale[BNA ? HID : 1], s_shift[BNA ? HID : 1];
    const int t = threadIdx.x;
    if (BNA) {
        if (t < HID) {
            float mean = bn_sums[t] / M;
            float istd = rsqrtf(bn_sums[HID + t] / M - mean * mean + EPSV);
            float s = istd * bn_g[t];
            s_scale[t] = s;
            s_shift[t] = bn_b[t] - mean * s;
        }
        __syncthreads();
    }
    const int wave = t >> 6, lane = t & 63;
    const int row0 = blockIdx.y * TM, col0 = blockIdx.x * 128;
    const int wm = (TM == 128) ? ((wave & 1) << 6) : 0;
    const int wn = (TM == 128) ? ((wave >> 1) << 6) : (wave << 5);
    const int lm = lane & 15, lk = (lane >> 4) << 3;
    constexpr int APASS = TM / 64;
    f32x4 acc[4][BNF] = {};
    for (int k0 = 0; k0 < K; k0 += 32) {
        u16x8 av[APASS], wv[2];
#pragma unroll
        for (int i = 0; i < APASS; i++) {
            int c = t + (i << 8);
            int r = c >> 2, ko = (c & 3) << 3;
            u16x8 zv = {};
            int gr = row0 + r;
            av[i] = (gr < M) ? *(const u16x8*)&A[(size_t)gr * K + k0 + ko] : zv;
            if (BNA) {
#pragma unroll
                for (int j = 0; j < 8; j++) {
                    int kc = k0 + ko + j;
                    float v = fmaxf(bf2f(av[i][j]) * s_scale[kc] + s_shift[kc], 0.f);
                    av[i][j] = f2bf(v);
                }
            }
        }
#pragma unroll
        for (int i = 0; i < 2; i++) {
            int c = t + (i << 8);
            int r = c >> 2, ko = (c & 3) << 3;
            wv[i] = *(const u16x8*)&Wt[(size_t)(col0 + r) * K + k0 + ko];
        }
        __syncthreads();
#pragma unroll
        for (int i = 0; i < APASS; i++) {
            int c = t + (i << 8);
            int r = c >> 2, ko = (c & 3) << 3;
            *(u16x8*)&As[r][ko] = av[i];
        }
#pragma unroll
        for (int i = 0; i < 2; i++) {
            int c = t + (i << 8);
            int r = c >> 2, ko = (c & 3) << 3;
            *(u16x8*)&Bs[r][ko] = wv[i];
        }
        __syncthreads();
        bf16x8 af[4], bfm[BNF];
#pragma unroll
        for (int i = 0; i < 4; i++) af[i]  = *(const bf16x8*)&As[wm + (i << 4) + lm][lk];
#pragma unroll
        for (int j = 0; j < BNF; j++) bfm[j] = *(const bf16x8*)&Bs[wn + (j << 4) + lm][lk];
#pragma unroll
        for (int i = 0; i < 4; i++)
#pragma unroll
            for (int j = 0; j < BNF; j++)
                acc[i][j] = __builtin_amdgcn_mfma_f32_16x16x32_bf16(af[i], bfm[j], acc[i][j], 0, 0, 0);
    }
    const int lr4 = (lane >> 4) << 2;
    float s1[BNF], s2[BNF];
#pragma unroll
    for (int j = 0; j < BNF; j++) { s1[j] = 0.f; s2[j] = 0.f; }
#pragma unroll
    for (int j = 0; j < BNF; j++) {
        int col = col0 + wn + (j << 4) + lm;
        float bv = BIAS2 ? ((col < 256) ? biasL[col] : biasR[col - 256]) : biasL[col];
#pragma unroll
        for (int i = 0; i < 4; i++) {
#pragma unroll
            for (int r = 0; r < 4; r++) {
                int row = row0 + wm + (i << 4) + lr4 + r;
                if (row < M) {
                    float v = acc[i][j][r] + bv;
                    Cout[(size_t)row * N + col] = f2bf(v);
                    if (STATS) { s1[j] += v; s2[j] += v * v; }
                }
            }
        }
    }
    if (STATS) {
#pragma unroll
        for (int j = 0; j < BNF; j++) {
            s1[j] += __shfl_xor(s1[j], 16, 64); s1[j] += __shfl_xor(s1[j], 32, 64);
            s2[j] += __shfl_xor(s2[j], 16, 64); s2[j] += __shfl_xor(s2[j], 32, 64);
        }
        if ((lane >> 4) == 0) {
#pragma unroll
            for (int j = 0; j < BNF; j++) {
                int col = col0 + wn + (j << 4) + lm;
                atomicAdd(&stats_sums[col], s1[j]);
                atomicAdd(&stats_sums[HID + col], s2[j]);
            }
        }
    }
}

// ========== fused ATTConv (GATv2): flash softmax, 2 waves per node ==========
// Block = 256 threads = 4 waves = 2 nodes x 2 half-waves. Each wave runs the
// online softmax over half the node's edge list; halves merge via LDS with
// the standard flash rescale; even wave runs epilogue + alpha.
#define ATT_CAP 192
template <int CONCAT, int WITH_ALPHA>
__global__ __launch_bounds__(256) void k_att_fused(const ushort4* __restrict__ Q,
                                                   const int* __restrict__ rowptr,
                                                   const int* __restrict__ plist,
                                                   const int* __restrict__ other,
                                                   const float* __restrict__ att,
                                                   const float* __restrict__ bias,
                                                   void* __restrict__ outp,
                                                   float* __restrict__ alpha_out) {
    __shared__ float s_lg[WITH_ALPHA ? 2 : 1][WITH_ALPHA ? ATT_CAP : 1][2];
    __shared__ float comb[2][64][6];   // odd half publishes m,ssum,acc[4]
    const int t = threadIdx.x;
    const int wave = t >> 6, l = t & 63;
    const int nl = wave >> 1;            // node-local (0,1)
    const int half = wave & 1;
    const int n = blockIdx.x * 2 + nl;   // N_NODES even
    const int h = l >> 5;
    ushort4 ur = Q[((size_t)n << 7) + 64 + l];   // xr slice
    float xr4[4] = {bf2f(ur.x), bf2f(ur.y), bf2f(ur.z), bf2f(ur.w)};
    const float* ap = &att[h * HID + ((l & 31) << 2)];
    float at4[4] = {ap[0], ap[1], ap[2], ap[3]};
    const int p0n = rowptr[n], p1n = rowptr[n + 1];
    const int cnt = p1n - p0n;
    const int mid = p0n + (cnt >> 1);
    const int my0 = half ? mid : p0n;
    const int my1 = half ? p1n : mid;

    float m = -INFINITY, ssum = 0.f;
    float acc[4] = {0.f, 0.f, 0.f, 0.f};

#define ATT_SRC(p) (WITH_ALPHA ? other[plist[p]] : plist[p])

#define ATT_LOGIT(uv, x4, tl) do { \
        x4[0] = bf2f(uv.x); x4[1] = bf2f(uv.y); x4[2] = bf2f(uv.z); x4[3] = bf2f(uv.w); \
        float v0 = x4[0] + xr4[0]; v0 = (v0 > 0.f) ? v0 : 0.2f * v0; \
        float v1 = x4[1] + xr4[1]; v1 = (v1 > 0.f) ? v1 : 0.2f * v1; \
        float v2 = x4[2] + xr4[2]; v2 = (v2 > 0.f) ? v2 : 0.2f * v2; \
        float v3 = x4[3] + xr4[3]; v3 = (v3 > 0.f) ? v3 : 0.2f * v3; \
        tl = at4[0] * v0 + at4[1] * v1 + at4[2] * v2 + at4[3] * v3; \
    } while (0)

    int p = my0;
    for (; p + 4 <= my1; p += 4) {
        float x4[4][4], tl[4];
        ushort4 uv[4];
        int ss[4];
#pragma unroll
        for (int j = 0; j < 4; j++) ss[j] = ATT_SRC(p + j);
#pragma unroll
        for (int j = 0; j < 4; j++) uv[j] = Q[((size_t)ss[j] << 7) + l];
#pragma unroll
        for (int j = 0; j < 4; j++) ATT_LOGIT(uv[j], x4[j], tl[j]);
#pragma unroll
        for (int k = 1; k <= 16; k <<= 1) {
#pragma unroll
            for (int j = 0; j < 4; j++) tl[j] += __shfl_xor(tl[j], k, 64);
        }
        if (WITH_ALPHA && (l & 31) == 0) {
#pragma unroll
            for (int j = 0; j < 4; j++)
                if (p + j - p0n < ATT_CAP) s_lg[nl][p + j - p0n][h] = tl[j];
        }
        float tmax = fmaxf(fmaxf(tl[0], tl[1]), fmaxf(tl[2], tl[3]));
        float mn = fmaxf(m, tmax);
        float sc = __expf(m - mn);
        float w0 = __expf(tl[0] - mn), w1 = __expf(tl[1] - mn);
        float w2 = __expf(tl[2] - mn), w3 = __expf(tl[3] - mn);
        ssum = ssum * sc + (w0 + w1 + w2 + w3);
#pragma unroll
        for (int c = 0; c < 4; c++)
            acc[c] = acc[c] * sc + w0 * x4[0][c] + w1 * x4[1][c] + w2 * x4[2][c] + w3 * x4[3][c];
        m = mn;
    }
    for (; p < my1; p++) {
        float x4[4], tl;
        ushort4 uv = Q[((size_t)ATT_SRC(p) << 7) + l];
        ATT_LOGIT(uv, x4, tl);
#pragma unroll
        for (int k = 1; k <= 16; k <<= 1) tl += __shfl_xor(tl, k, 64);
        float mn = fmaxf(m, tl);
        float sc = __expf(m - mn);
        float w  = __expf(tl - mn);
        ssum = ssum * sc + w;
#pragma unroll
        for (int c = 0; c < 4; c++) acc[c] = acc[c] * sc + w * x4[c];
        m = mn;
        if (WITH_ALPHA && (p - p0n) < ATT_CAP && (l & 31) == 0) s_lg[nl][p - p0n][h] = tl;
    }

    // ---- flash-combine the two halves via LDS ----
    if (half == 1) {
        comb[nl][l][0] = m; comb[nl][l][1] = ssum;
        comb[nl][l][2] = acc[0]; comb[nl][l][3] = acc[1];
        comb[nl][l][4] = acc[2]; comb[nl][l][5] = acc[3];
    }
    __syncthreads();
    if (half == 1) return;
    {
        float m2v = comb[nl][l][0], s2v = comb[nl][l][1];
        float mm = fmaxf(m, m2v);
        float sc1 = (m   > -INFINITY) ? __expf(m   - mm) : 0.f;
        float sc2 = (m2v > -INFINITY) ? __expf(m2v - mm) : 0.f;
        ssum = ssum * sc1 + s2v * sc2;
#pragma unroll
        for (int c = 0; c < 4; c++)
            acc[c] = acc[c] * sc1 + comb[nl][l][2 + c] * sc2;
        m = mm;
    }
    float inv = 1.f / (ssum + 1e-16f);

    // ---- alpha output (att2): parallel from LDS cache (even wave only) ----
    if (WITH_ALPHA) {
        float m_o   = __shfl_xor(m, 32, 64);
        float inv_o = __shfl_xor(inv, 32, 64);
        float m2[2], i2[2];
        m2[h] = m; m2[1 - h] = m_o;
        i2[h] = inv; i2[1 - h] = inv_o;
        int ccnt = (cnt < ATT_CAP) ? cnt : ATT_CAP;
        for (int i = l; i < ccnt * 2; i += 64) {
            int idx = i >> 1, hh = i & 1;
            float a = __expf(s_lg[nl][idx][hh] - m2[hh]) * i2[hh];
            alpha_out[plist[p0n + idx] * HEADS + hh] = a;
        }
        // overflow fallback (deg > ATT_CAP): serial recompute (practically never taken)
        for (int pp = p0n + ATT_CAP; pp < p1n; pp++) {
            float x4[4], tl;
            ushort4 uv = Q[((size_t)ATT_SRC(pp) << 7) + l];
            ATT_LOGIT(uv, x4, tl);
#pragma unroll
            for (int k = 1; k <= 16; k <<= 1) tl += __shfl_xor(tl, k, 64);
            if ((l & 31) == 0) alpha_out[plist[pp] * HEADS + h] = __expf(tl - m) * inv;
        }
    }

    // ---- epilogue ----
    if (CONCAT) {
        const float* bp = &bias[l << 2];
        ushort4 o;
        o.x = f2bf(fmaxf(acc[0] * inv + bp[0], 0.f));
        o.y = f2bf(fmaxf(acc[1] * inv + bp[1], 0.f));
        o.z = f2bf(fmaxf(acc[2] * inv + bp[2], 0.f));
        o.w = f2bf(fmaxf(acc[3] * inv + bp[3], 0.f));
        ((ushort4*)outp)[((size_t)n << 6) + l] = o;
    } else {
        float o[4];
#pragma unroll
        for (int i = 0; i < 4; i++) {
            float v = acc[i] * inv;
            float other_v = __shfl_xor(v, 32, 64);
            o[i] = 0.5f * (v + other_v);
        }
        if (l < 32) {
            const float* bp = &bias[(l & 31) << 2];
            float4 ov;
            ov.x = fmaxf(o[0] + bp[0], 0.f); ov.y = fmaxf(o[1] + bp[1], 0.f);
            ov.z = fmaxf(o[2] + bp[2], 0.f); ov.w = fmaxf(o[3] + bp[3], 0.f);
            ((float4*)outp)[((size_t)n << 5) + l] = ov;
        }
    }
#undef ATT_SRC
#undef ATT_LOGIT
}

// ================= pooling over sorted batch_index (node-parallel) =================
template <int C>
__global__ __launch_bounds__(256) void k_pool_atomic(const float* __restrict__ X,
                                                     const int* __restrict__ batch,
                                                     float* __restrict__ pool, int npb) {
    const int RP = 256 / C;
    int c = threadIdx.x & (C - 1);
    int rofs = threadIdx.x / C;
    int i0 = blockIdx.x * npb;
    int i1 = min(i0 + npb, N_NODES);
    float acc = 0.f;
    int gcur = -1;
    for (int i = i0 + rofs; i < i1; i += RP) {
        int g = batch[i];
        if (g != gcur) {
            if (gcur >= 0) atomicAdd(&pool[gcur * C + c], acc);
            acc = 0.f; gcur = g;
        }
        acc += X[(size_t)i * C + c];
    }
    if (gcur >= 0) atomicAdd(&pool[gcur * C + c], acc);
}

// ================= final prediction head =================
__global__ void k_head(const float* __restrict__ pool0, const float* __restrict__ poolL,
                       const float* __restrict__ p0w, const float* __restrict__ p0b,
                       const float* __restrict__ pLw, const float* __restrict__ pLb,
                       const float* __restrict__ ow, const float* __restrict__ ob,
                       float* __restrict__ outputs) {
    int g = blockIdx.x;
    int m = threadIdx.x;
    __shared__ float sh[MIDD];
    if (m < MIDD) {
        float s = p0b[m] + pLb[m];
        for (int k = 0; k < F_INN; k++) s += pool0[g * F_INN + k] * p0w[k * MIDD + m];
        for (int k = 0; k < HID; k++)  s += poolL[g * HID + k] * pLw[k * MIDD + m];
        sh[m] = fmaxf(s, 0.f);
    }
    __syncthreads();
    if (m == 0) {
        float s = ob[0];
        for (int k = 0; k < MIDD; k++) s += sh[k] * ow[k];
        outputs[g] = s;
    }
}

extern "C" void kernel_launch(void* const* d_in, const int* in_sizes, int n_in,
                              void* d_out, int out_size, void* d_ws, size_t ws_size,
                              hipStream_t stream) {
    // ---- inputs ----
    const float* x      = (const float*)d_in[0];
    const int*   ei     = (const int*)d_in[1];
    const int*   aei    = (const int*)d_in[2];
    const int*   batch  = (const int*)d_in[3];
    const float* g0_w1  = (const float*)d_in[4];
    const float* g0_b1  = (const float*)d_in[5];
    const float* g0_bng = (const float*)d_in[6];
    const float* g0_bnb = (const float*)d_in[7];
    const float* g0_w2  = (const float*)d_in[8];
    const float* g0_b2  = (const float*)d_in[9];
    const float* g1_w1  = (const float*)d_in[10];
    const float* g1_b1  = (const float*)d_in[11];
    const float* g1_bng = (const float*)d_in[12];
    const float* g1_bnb = (const float*)d_in[13];
    const float* g1_w2  = (const float*)d_in[14];
    const float* g1_b2  = (const float*)d_in[15];
    const float* bn0_g  = (const float*)d_in[16];
    const float* bn0_b  = (const float*)d_in[17];
    const float* bn1_g  = (const float*)d_in[18];
    const float* bn1_b  = (const float*)d_in[19];
    const float* a1_wl  = (const float*)d_in[20];
    const float* a1_bl  = (const float*)d_in[21];
    const float* a1_wr  = (const float*)d_in[22];
    const float* a1_br  = (const float*)d_in[23];
    const float* a1_att = (const float*)d_in[24];
    const float* a1_bias= (const float*)d_in[25];
    const float* a2_wl  = (const float*)d_in[26];
    const float* a2_bl  = (const float*)d_in[27];
    const float* a2_wr  = (const float*)d_in[28];
    const float* a2_br  = (const float*)d_in[29];
    const float* a2_att = (const float*)d_in[30];
    const float* a2_bias= (const float*)d_in[31];
    const float* p0w    = (const float*)d_in[32];
    const float* p0b    = (const float*)d_in[33];
    const float* pLw    = (const float*)d_in[34];
    const float* pLb    = (const float*)d_in[35];
    const float* ow     = (const float*)d_in[36];
    const float* ob     = (const float*)d_in[37];

    // ---- outputs ----
    float* out_head  = (float*)d_out;
    float* atten_out = out_head + G_GR;
    float* alpha_out = atten_out + (size_t)N_NODES * HID;

    // ---- workspace ----
    float* ws = (float*)d_ws;
    float* sums4 = ws;                                 // 4*256 (s0|s1|s2|s3)
    float* pool0 = sums4 + 4 * 256;                    // G*64
    float* poolL = pool0 + G_GR * F_INN;               // G*128
    int*   btot  = (int*)(poolL + G_GR * HID);         // 3*NBUK (zeroed)
    const size_t zero_bytes = (4 * 256 + G_GR * F_INN + G_GR * HID + 3 * NBUK) * 4;

    int* ip = btot + 3 * NBUK;
    int* bstart = ip; ip += 3 * (NBUK + 1);
    int* bcur   = ip; ip += 3 * NBUK;
    int* rowptr[3]; int* payload[3];
    for (int c = 0; c < 3; c++) {
        rowptr[c]  = ip; ip += N_NODES + 1;
        payload[c] = ip; ip += E_EDGES;
    }
    int2* tmp3 = (int2*)ip; ip += 2 * 3 * E_EDGES;     // [3][E] int2
    const size_t NB = (size_t)N_NODES * HC;
    unsigned short* B1 = (unsigned short*)ip;          // [N,HC] bf16
    unsigned short* B2 = B1 + NB;                      // [N,HC] bf16
    unsigned short* Qb = B2 + NB;                      // [N,512] bf16 merged projections
    unsigned short* g0w1t = Qb + 2 * NB;
    unsigned short* g0w2t = g0w1t + 128 * 64;
    unsigned short* g1w1t = g0w2t + 128 * 128;
    unsigned short* g1w2t = g1w1t + 128 * 128;
    unsigned short* a1wlt = g1w2t + 128 * 128;         // [256,128]
    unsigned short* a1wrt = a1wlt + 256 * 128;         // contiguous -> [512,128]
    unsigned short* a2wlt = a1wrt + 256 * 128;         // [256,256]
    unsigned short* a2wrt = a2wlt + 256 * 256;         // contiguous -> [512,256]

    const int* e_row = ei;
    const int* e_col = ei + E_EDGES;
    const int* a_src = aei;
    const int* a_dst = aei + E_EDGES;

    const int TB = 256;
#define GRID1(n) dim3(CDIV((n), TB))

    // ===== weight transpose+cast =====
    {
        WtJobs jobs;
        jobs.j[0] = {g0_w1, g0w1t, F_INN, HID};
        jobs.j[1] = {g0_w2, g0w2t, HID,   HID};
        jobs.j[2] = {g1_w1, g1w1t, HID,   HID};
        jobs.j[3] = {g1_w2, g1w2t, HID,   HID};
        jobs.j[4] = {a1_wl, a1wlt, HID,   HC};
        jobs.j[5] = {a1_wr, a1wrt, HID,   HC};
        jobs.j[6] = {a2_wl, a2wlt, HC,    HC};
        jobs.j[7] = {a2_wr, a2wrt, HC,    HC};
        k_wt_cast<<<dim3(32, 8), TB, 0, stream>>>(jobs);
    }

    // ===== zero sums/pools/btot in one shot; build 3 CSRs (bucket-granular) =====
    hipMemsetAsync(sums4, 0, zero_bytes, stream);
    {
        Csr3 c;
        c.key[0] = e_row; c.other[0] = e_col;
        c.key[1] = e_col; c.other[1] = e_row;
        c.key[2] = a_dst; c.other[2] = a_src;
        c.btot = btot; c.bstart = bstart; c.bcur = bcur; c.tmp = tmp3;
        for (int i = 0; i < 3; i++) { c.rowptr[i] = rowptr[i]; c.out[i] = payload[i]; }
        k_bhist<<<dim3(CDIV(E_EDGES, 4096), 3), TB, 0, stream>>>(c);
        k_bscan<<<dim3(1), TB, 0, stream>>>(c);
        k_bucketA<<<dim3(CDIV(E_EDGES, 4096), 3), TB, 0, stream>>>(c);
        k_bucketB<<<dim3(NBUK, 3), TB, 0, stream>>>(c);
    }

    const dim3 gemm_g1(1, CDIV(N_NODES, 64));    // N=128, TM=64 (313 blocks)
    const dim3 gemm_gq(4, CDIV(N_NODES, 128));   // N=512, TM=128 (628 blocks)
    const float* NOF = nullptr;

    // ===== GANConv 0 (ping-pong B1/B2 as [N,128]) =====
    k_gather_f32<<<GRID1(N_NODES * 16), TB, 0, stream>>>((const float4*)x, rowptr[0], payload[0], B1);
    k_mfma_gemm<1, 0, 64, 0><<<gemm_g1, TB, 0, stream>>>(B1, g0w1t, g0_b1, NOF, B2, N_NODES, F_INN, HID,
                                                         sums4 + 0, NOF, NOF, NOF);
    k_mfma_gemm<1, 1, 64, 0><<<gemm_g1, TB, 0, stream>>>(B2, g0w2t, g0_b2, NOF, B1, N_NODES, HID, HID,
                                                         sums4 + 256, sums4 + 0, g0_bng, g0_bnb);
    // raw2 (pre-bn0) in B1

    // ===== GANConv 1 =====
    k_gather_bn<<<GRID1(N_NODES * 16), TB, 0, stream>>>((const u16x8*)B1, rowptr[0], payload[0],
                                                        sums4 + 256, bn0_g, bn0_b, (u16x8*)B2);
    k_mfma_gemm<1, 0, 64, 0><<<gemm_g1, TB, 0, stream>>>(B2, g1w1t, g1_b1, NOF, B1, N_NODES, HID, HID,
                                                         sums4 + 512, NOF, NOF, NOF);
    k_mfma_gemm<1, 1, 64, 0><<<gemm_g1, TB, 0, stream>>>(B1, g1w2t, g1_b2, NOF, B2, N_NODES, HID, HID,
                                                         sums4 + 768, sums4 + 512, g1_bng, g1_bnb);
    // raw4 (pre-bn1 = h2 raw) in B2

    // ===== ATTConv 1 (dst=e_col, concat=True): merged wl|wr GEMM -> Q [N,512] =====
    k_mfma_gemm<0, 1, 128, 1><<<gemm_gq, TB, 0, stream>>>(B2, a1wlt, a1_bl, a1_br, Qb, N_NODES, HID, 512,
                                                          nullptr, sums4 + 768, bn1_g, bn1_b);
    k_att_fused<1, 0><<<dim3(N_NODES / 2), TB, 0, stream>>>(
        (const ushort4*)Qb, rowptr[1], payload[1], nullptr, a1_att, a1_bias, (void*)B1, nullptr);
    // emb bf16 in B1 [N,HC]

    // ===== ATTConv 2 (dst=a_dst, concat=False): merged GEMM K=256 -> Q =====
    k_mfma_gemm<0, 0, 128, 1><<<gemm_gq, TB, 0, stream>>>(B1, a2wlt, a2_bl, a2_br, Qb, N_NODES, HC, 512,
                                                          nullptr, NOF, NOF, NOF);
    k_att_fused<0, 1><<<dim3(N_NODES / 2), TB, 0, stream>>>(
        (const ushort4*)Qb, rowptr[2], payload[2], a_src, a2_att, a2_bias, (void*)atten_out, alpha_out);

    // ===== pooling + head =====
    {
        const int npb = 64;  // 313 blocks
        k_pool_atomic<F_INN><<<dim3(CDIV(N_NODES, npb)), TB, 0, stream>>>(x, batch, pool0, npb);
        k_pool_atomic<HID><<<dim3(CDIV(N_NODES, npb)), TB, 0, stream>>>(atten_out, batch, poolL, npb);
    }
    k_head<<<dim3(G_GR), 64, 0, stream>>>(pool0, poolL, p0w, p0b, pLw, pLb, ow, ob, out_head);
}

// Round 14
// 427.087 us; speedup vs baseline: 1.0637x; 1.0637x over previous
//
#include <hip/hip_runtime.h>
#include <hip/hip_bf16.h>

#define N_NODES 20000
#define E_EDGES 320000
#define F_INN   64
#define HID     128
#define HEADS   2
#define HC      (HEADS * HID)   // 256
#define G_GR    64
#define MIDD    32
#define EPSV    1e-5f
#define NBUK    79              // ceil(20000/256); bucket = node >> 8

#define CDIV(a, b) (((a) + (b) - 1) / (b))

typedef __attribute__((ext_vector_type(8))) short          bf16x8;  // MFMA A/B frag
typedef __attribute__((ext_vector_type(4))) float          f32x4;   // MFMA C/D frag
typedef __attribute__((ext_vector_type(8))) unsigned short u16x8;

// ---------- bf16 helpers (RNE) ----------
__device__ inline float bf2f(unsigned short u) { return __uint_as_float((unsigned)u << 16); }
__device__ inline unsigned short f2bf(float f) {
    unsigned u = __float_as_uint(f);
    unsigned r = u + 0x7FFFu + ((u >> 16) & 1u);
    return (unsigned short)(r >> 16);
}

// ================= CSR construction (3 CSRs, bucket-granular two-pass) ========
struct Csr3 {
    const int* key[3];
    const int* other[3];   // payload source for y=0,1; y=2 stores edge id
    int* btot;      // [3*NBUK] bucket totals (zeroed)
    int* bstart;    // [3*(NBUK+1)] bucket starts
    int* bcur;      // [3*NBUK] bucket cursors
    int* rowptr[3]; // [N+1] (written by bucketB)
    int* out[3];    // [E] payload (final, CSR order)
    int2* tmp;      // [3*E] (key,payload) bucket-partitioned
};

__global__ __launch_bounds__(256) void k_bhist(Csr3 c) {
    __shared__ int hist[NBUK];
    const int y = blockIdx.y;
    const int chunk0 = blockIdx.x * 4096;
    const int t = threadIdx.x;
    for (int i = t; i < NBUK; i += 256) hist[i] = 0;
    __syncthreads();
#pragma unroll
    for (int i = 0; i < 16; i++) {
        int e = chunk0 + (i << 8) + t;
        if (e < E_EDGES) atomicAdd(&hist[c.key[y][e] >> 8], 1);
    }
    __syncthreads();
    for (int i = t; i < NBUK; i += 256)
        if (hist[i] > 0) atomicAdd(&c.btot[y * NBUK + i], hist[i]);
}

__global__ void k_bscan(Csr3 c) {
    __shared__ int sh[3 * NBUK];
    int t = threadIdx.x;
    for (int i = t; i < 3 * NBUK; i += 256) sh[i] = c.btot[i];
    __syncthreads();
    if (t < 3) {
        int run = 0;
        int* bs = c.bstart + t * (NBUK + 1);
        for (int b = 0; b < NBUK; b++) {
            bs[b] = run;
            c.bcur[t * NBUK + b] = run;
            run += sh[t * NBUK + b];
        }
        bs[NBUK] = run;
    }
}

__global__ __launch_bounds__(256) void k_bucketA(Csr3 c) {
    __shared__ int hist[NBUK], base[NBUK], off[NBUK];
    const int y = blockIdx.y;
    const int chunk0 = blockIdx.x * 4096;
    const int t = threadIdx.x;
    for (int i = t; i < NBUK; i += 256) { hist[i] = 0; off[i] = 0; }
    __syncthreads();
    int keys[16], vals[16], bks[16];
#pragma unroll
    for (int i = 0; i < 16; i++) {
        int e = chunk0 + (i << 8) + t;
        bool ok = (e < E_EDGES);
        int k = ok ? c.key[y][e] : 0;
        keys[i] = k;
        vals[i] = ok ? ((y == 2) ? e : c.other[y][e]) : 0;
        bks[i] = ok ? (k >> 8) : -1;
        if (ok) atomicAdd(&hist[k >> 8], 1);
    }
    __syncthreads();
    if (t < NBUK && hist[t] > 0) base[t] = atomicAdd(&c.bcur[y * NBUK + t], hist[t]);
    __syncthreads();
    int2* ty = c.tmp + (size_t)y * E_EDGES;
#pragma unroll
    for (int i = 0; i < 16; i++) {
        int b = bks[i];
        if (b >= 0) {
            int o = atomicAdd(&off[b], 1);
            ty[base[b] + o] = make_int2(keys[i], vals[i]);
        }
    }
}

__global__ __launch_bounds__(256) void k_bucketB(Csr3 c) {
    __shared__ int cnt[256], lbase[256], run[256];
    const int y = blockIdx.y;
    const int b = blockIdx.x;
    const int nbase = b << 8;
    const int t = threadIdx.x;
    cnt[t] = 0; run[t] = 0;
    __syncthreads();
    const int bs = c.bstart[y * (NBUK + 1) + b];
    const int be = c.bstart[y * (NBUK + 1) + b + 1];
    const int2* ty = c.tmp + (size_t)y * E_EDGES;
    for (int i = bs + t; i < be; i += 256)
        atomicAdd(&cnt[ty[i].x - nbase], 1);
    __syncthreads();
    int v = cnt[t];
    lbase[t] = v;
    __syncthreads();
    for (int off = 1; off < 256; off <<= 1) {
        int u = (t >= off) ? lbase[t - off] : 0;
        __syncthreads();
        lbase[t] += u;
        __syncthreads();
    }
    int excl = lbase[t] - v;
    __syncthreads();
    lbase[t] = excl;
    __syncthreads();
    int n = nbase + t;
    if (n < N_NODES) c.rowptr[y][n] = bs + excl;
    if (b == NBUK - 1 && t == 0) c.rowptr[y][N_NODES] = E_EDGES;
    int* outy = c.out[y];
    for (int i = bs + t; i < be; i += 256) {
        int2 kv = ty[i];
        int k = kv.x - nbase;
        int o = atomicAdd(&run[k], 1);
        outy[bs + lbase[k] + o] = kv.y;
    }
}

// ===== GANConv0 aggregation: z[n] = bf16(x[n] + sum x[srcs]) , fp32 input, unroll-4 =====
__global__ __launch_bounds__(256) void k_gather_f32(const float4* __restrict__ x,
                                                    const int* __restrict__ rowptr,
                                                    const int* __restrict__ srcs,
                                                    unsigned short* __restrict__ z) {
    int gid = blockIdx.x * blockDim.x + threadIdx.x;
    int n = gid >> 4;
    if (n >= N_NODES) return;
    int q = gid & 15;
    float4 acc = x[((size_t)n << 4) + q];
    float4 a1 = make_float4(0.f, 0.f, 0.f, 0.f), a2 = a1, a3 = a1;
    int p = rowptr[n], p1 = rowptr[n + 1];
    for (; p + 4 <= p1; p += 4) {
        float4 v0 = x[((size_t)srcs[p + 0] << 4) + q];
        float4 v1 = x[((size_t)srcs[p + 1] << 4) + q];
        float4 v2 = x[((size_t)srcs[p + 2] << 4) + q];
        float4 v3 = x[((size_t)srcs[p + 3] << 4) + q];
        acc.x += v0.x; acc.y += v0.y; acc.z += v0.z; acc.w += v0.w;
        a1.x += v1.x; a1.y += v1.y; a1.z += v1.z; a1.w += v1.w;
        a2.x += v2.x; a2.y += v2.y; a2.z += v2.z; a2.w += v2.w;
        a3.x += v3.x; a3.y += v3.y; a3.z += v3.z; a3.w += v3.w;
    }
    for (; p < p1; p++) {
        float4 v = x[((size_t)srcs[p] << 4) + q];
        acc.x += v.x; acc.y += v.y; acc.z += v.z; acc.w += v.w;
    }
    acc.x += a1.x + a2.x + a3.x; acc.y += a1.y + a2.y + a3.y;
    acc.z += a1.z + a2.z + a3.z; acc.w += a1.w + a2.w + a3.w;
    ushort4 o;
    o.x = f2bf(acc.x); o.y = f2bf(acc.y); o.z = f2bf(acc.z); o.w = f2bf(acc.w);
    *(ushort4*)&z[((size_t)n << 6) + (q << 2)] = o;
}

// ===== GANConv1 aggregation with fused BN+relu on load, unroll-4 =====
__global__ __launch_bounds__(256) void k_gather_bn(const u16x8* __restrict__ raw,
                                                   const int* __restrict__ rowptr,
                                                   const int* __restrict__ srcs,
                                                   const float* __restrict__ bn_sums,
                                                   const float* __restrict__ g,
                                                   const float* __restrict__ b,
                                                   u16x8* __restrict__ z) {
    int gid = blockIdx.x * blockDim.x + threadIdx.x;
    int n = gid >> 4;
    if (n >= N_NODES) return;
    int q = gid & 15;
    float sc[8], sh[8];
#pragma unroll
    for (int i = 0; i < 8; i++) {
        int c = (q << 3) + i;
        float mean = bn_sums[c] / N_NODES;
        float istd = rsqrtf(bn_sums[HID + c] / N_NODES - mean * mean + EPSV);
        float s = istd * g[c];
        sc[i] = s;
        sh[i] = b[c] - mean * s;
    }
    u16x8 u0 = raw[((size_t)n << 4) + q];
    float acc[8];
#pragma unroll
    for (int i = 0; i < 8; i++) acc[i] = fmaxf(bf2f(u0[i]) * sc[i] + sh[i], 0.f);
    int p = rowptr[n], p1 = rowptr[n + 1];
    for (; p + 4 <= p1; p += 4) {
        u16x8 v0 = raw[((size_t)srcs[p + 0] << 4) + q];
        u16x8 v1 = raw[((size_t)srcs[p + 1] << 4) + q];
        u16x8 v2 = raw[((size_t)srcs[p + 2] << 4) + q];
        u16x8 v3 = raw[((size_t)srcs[p + 3] << 4) + q];
#pragma unroll
        for (int i = 0; i < 8; i++) {
            acc[i] += fmaxf(bf2f(v0[i]) * sc[i] + sh[i], 0.f)
                    + fmaxf(bf2f(v1[i]) * sc[i] + sh[i], 0.f)
                    + fmaxf(bf2f(v2[i]) * sc[i] + sh[i], 0.f)
                    + fmaxf(bf2f(v3[i]) * sc[i] + sh[i], 0.f);
        }
    }
    for (; p < p1; p++) {
        u16x8 v = raw[((size_t)srcs[p] << 4) + q];
#pragma unroll
        for (int i = 0; i < 8; i++) acc[i] += fmaxf(bf2f(v[i]) * sc[i] + sh[i], 0.f);
    }
    u16x8 o;
#pragma unroll
    for (int i = 0; i < 8; i++) o[i] = f2bf(acc[i]);
    z[((size_t)n << 4) + q] = o;
}

// ===== weight prep: Wt[n][k] = bf16(W[k][n]) for 8 weights in one launch =====
struct WtJob  { const float* src; unsigned short* dst; int K; int N; };
struct WtJobs { WtJob j[8]; };
__global__ void k_wt_cast(WtJobs jobs) {
    WtJob jb = jobs.j[blockIdx.y];
    int total = jb.K * jb.N;
    for (int i = blockIdx.x * blockDim.x + threadIdx.x; i < total; i += gridDim.x * blockDim.x) {
        int nn = i / jb.K, kk = i - nn * jb.K;
        jb.dst[i] = f2bf(jb.src[(size_t)kk * jb.N + nn]);
    }
}

// ===== MFMA bf16 GEMM: C[M,N] = A'[M,K] @ Wt[N,K]^T + bias; bf16 out =====
template <int STATS, int BNA, int TM, int BIAS2>
__global__ __launch_bounds__(256) void k_mfma_gemm(const unsigned short* __restrict__ A,
                                                   const unsigned short* __restrict__ Wt,
                                                   const float* __restrict__ biasL,
                                                   const float* __restrict__ biasR,
                                                   unsigned short* __restrict__ Cout,
                                                   int M, int K, int N,
                                                   float* __restrict__ stats_sums,
                                                   const float* __restrict__ bn_sums,
                                                   const float* __restrict__ bn_g,
                                                   const float* __restrict__ bn_b) {
    constexpr int BNF = (TM == 128) ? 4 : 2;
    __shared__ unsigned short As[TM][40];
    __shared__ unsigned short Bs[128][40];
    __shared__ float s_scale[BNA ? HID : 1], s_shift[BNA ? HID : 1];
    const int t = threadIdx.x;
    if (BNA) {
        if (t < HID) {
            float mean = bn_sums[t] / M;
            float istd = rsqrtf(bn_sums[HID + t] / M - mean * mean + EPSV);
            float s = istd * bn_g[t];
            s_scale[t] = s;
            s_shift[t] = bn_b[t] - mean * s;
        }
        __syncthreads();
    }
    const int wave = t >> 6, lane = t & 63;
    const int row0 = blockIdx.y * TM, col0 = blockIdx.x * 128;
    const int wm = (TM == 128) ? ((wave & 1) << 6) : 0;
    const int wn = (TM == 128) ? ((wave >> 1) << 6) : (wave << 5);
    const int lm = lane & 15, lk = (lane >> 4) << 3;
    constexpr int APASS = TM / 64;
    f32x4 acc[4][BNF] = {};
    for (int k0 = 0; k0 < K; k0 += 32) {
        u16x8 av[APASS], wv[2];
#pragma unroll
        for (int i = 0; i < APASS; i++) {
            int c = t + (i << 8);
            int r = c >> 2, ko = (c & 3) << 3;
            u16x8 zv = {};
            int gr = row0 + r;
            av[i] = (gr < M) ? *(const u16x8*)&A[(size_t)gr * K + k0 + ko] : zv;
            if (BNA) {
#pragma unroll
                for (int j = 0; j < 8; j++) {
                    int kc = k0 + ko + j;
                    float v = fmaxf(bf2f(av[i][j]) * s_scale[kc] + s_shift[kc], 0.f);
                    av[i][j] = f2bf(v);
                }
            }
        }
#pragma unroll
        for (int i = 0; i < 2; i++) {
            int c = t + (i << 8);
            int r = c >> 2, ko = (c & 3) << 3;
            wv[i] = *(const u16x8*)&Wt[(size_t)(col0 + r) * K + k0 + ko];
        }
        __syncthreads();
#pragma unroll
        for (int i = 0; i < APASS; i++) {
            int c = t + (i << 8);
            int r = c >> 2, ko = (c & 3) << 3;
            *(u16x8*)&As[r][ko] = av[i];
        }
#pragma unroll
        for (int i = 0; i < 2; i++) {
            int c = t + (i << 8);
            int r = c >> 2, ko = (c & 3) << 3;
            *(u16x8*)&Bs[r][ko] = wv[i];
        }
        __syncthreads();
        bf16x8 af[4], bfm[BNF];
#pragma unroll
        for (int i = 0; i < 4; i++) af[i]  = *(const bf16x8*)&As[wm + (i << 4) + lm][lk];
#pragma unroll
        for (int j = 0; j < BNF; j++) bfm[j] = *(const bf16x8*)&Bs[wn + (j << 4) + lm][lk];
#pragma unroll
        for (int i = 0; i < 4; i++)
#pragma unroll
            for (int j = 0; j < BNF; j++)
                acc[i][j] = __builtin_amdgcn_mfma_f32_16x16x32_bf16(af[i], bfm[j], acc[i][j], 0, 0, 0);
    }
    const int lr4 = (lane >> 4) << 2;
    float s1[BNF], s2[BNF];
#pragma unroll
    for (int j = 0; j < BNF; j++) { s1[j] = 0.f; s2[j] = 0.f; }
#pragma unroll
    for (int j = 0; j < BNF; j++) {
        int col = col0 + wn + (j << 4) + lm;
        float bv = BIAS2 ? ((col < 256) ? biasL[col] : biasR[col - 256]) : biasL[col];
#pragma unroll
        for (int i = 0; i < 4; i++) {
#pragma unroll
            for (int r = 0; r < 4; r++) {
                int row = row0 + wm + (i << 4) + lr4 + r;
                if (row < M) {
                    float v = acc[i][j][r] + bv;
                    Cout[(size_t)row * N + col] = f2bf(v);
                    if (STATS) { s1[j] += v; s2[j] += v * v; }
                }
            }
        }
    }
    if (STATS) {
#pragma unroll
        for (int j = 0; j < BNF; j++) {
            s1[j] += __shfl_xor(s1[j], 16, 64); s1[j] += __shfl_xor(s1[j], 32, 64);
            s2[j] += __shfl_xor(s2[j], 16, 64); s2[j] += __shfl_xor(s2[j], 32, 64);
        }
        if ((lane >> 4) == 0) {
#pragma unroll
            for (int j = 0; j < BNF; j++) {
                int col = col0 + wn + (j << 4) + lm;
                atomicAdd(&stats_sums[col], s1[j]);
                atomicAdd(&stats_sums[HID + col], s2[j]);
            }
        }
    }
}

// ========== fused ATTConv (GATv2): single-pass flash-style online softmax ==========
// One wave per node (r11-best form); lane l -> channels 4l..4l+3, head h = l>>5.
// Q is the merged projection buffer [N,512]: xl = row[0:256), xr = row[256:512).
// Unroll-4 independent loads; per-edge online update (measured faster than
// group-wise r12 and two-wave r13 variants).
#define ATT_CAP 192
template <int CONCAT, int WITH_ALPHA>
__global__ __launch_bounds__(256) void k_att_fused(const ushort4* __restrict__ Q,
                                                   const int* __restrict__ rowptr,
                                                   const int* __restrict__ plist,
                                                   const int* __restrict__ other,
                                                   const float* __restrict__ att,
                                                   const float* __restrict__ bias,
                                                   void* __restrict__ outp,
                                                   float* __restrict__ alpha_out) {
    __shared__ float s_lg[WITH_ALPHA ? 4 : 1][WITH_ALPHA ? ATT_CAP : 1][2];
    const int t = threadIdx.x;
    const int wave = t >> 6, l = t & 63;
    const int n = blockIdx.x * 4 + wave;   // N_NODES % 4 == 0
    const int h = l >> 5;
    ushort4 ur = Q[((size_t)n << 7) + 64 + l];   // xr slice
    float xr4[4] = {bf2f(ur.x), bf2f(ur.y), bf2f(ur.z), bf2f(ur.w)};
    const float* ap = &att[h * HID + ((l & 31) << 2)];
    float at4[4] = {ap[0], ap[1], ap[2], ap[3]};
    const int p0 = rowptr[n], p1 = rowptr[n + 1];

    float m = -INFINITY, ssum = 0.f;
    float acc[4] = {0.f, 0.f, 0.f, 0.f};

#define ATT_SRC(p) (WITH_ALPHA ? other[plist[p]] : plist[p])

#define ATT_LOGIT(uv, x4, tl) do { \
        x4[0] = bf2f(uv.x); x4[1] = bf2f(uv.y); x4[2] = bf2f(uv.z); x4[3] = bf2f(uv.w); \
        float v0 = x4[0] + xr4[0]; v0 = (v0 > 0.f) ? v0 : 0.2f * v0; \
        float v1 = x4[1] + xr4[1]; v1 = (v1 > 0.f) ? v1 : 0.2f * v1; \
        float v2 = x4[2] + xr4[2]; v2 = (v2 > 0.f) ? v2 : 0.2f * v2; \
        float v3 = x4[3] + xr4[3]; v3 = (v3 > 0.f) ? v3 : 0.2f * v3; \
        tl = at4[0] * v0 + at4[1] * v1 + at4[2] * v2 + at4[3] * v3; \
    } while (0)

#define ATT_ONLINE(x4, tl, idx) do { \
        float mn = fmaxf(m, tl); \
        float sc = __expf(m - mn); \
        float w  = __expf(tl - mn); \
        ssum = ssum * sc + w; \
        acc[0] = acc[0] * sc + w * x4[0]; \
        acc[1] = acc[1] * sc + w * x4[1]; \
        acc[2] = acc[2] * sc + w * x4[2]; \
        acc[3] = acc[3] * sc + w * x4[3]; \
        m = mn; \
        if (WITH_ALPHA && (idx) < ATT_CAP && (l & 31) == 0) s_lg[wave][idx][h] = tl; \
    } while (0)

    int p = p0;
    for (; p + 4 <= p1; p += 4) {
        float x4[4][4], tl[4];
        ushort4 uv[4];
        int ss[4];
#pragma unroll
        for (int j = 0; j < 4; j++) ss[j] = ATT_SRC(p + j);
#pragma unroll
        for (int j = 0; j < 4; j++) uv[j] = Q[((size_t)ss[j] << 7) + l];
#pragma unroll
        for (int j = 0; j < 4; j++) ATT_LOGIT(uv[j], x4[j], tl[j]);
#pragma unroll
        for (int k = 1; k <= 16; k <<= 1) {
#pragma unroll
            for (int j = 0; j < 4; j++) tl[j] += __shfl_xor(tl[j], k, 64);
        }
#pragma unroll
        for (int j = 0; j < 4; j++) ATT_ONLINE(x4[j], tl[j], p + j - p0);
    }
    for (; p < p1; p++) {
        float x4[4], tl;
        ushort4 uv = Q[((size_t)ATT_SRC(p) << 7) + l];
        ATT_LOGIT(uv, x4, tl);
#pragma unroll
        for (int k = 1; k <= 16; k <<= 1) tl += __shfl_xor(tl, k, 64);
        ATT_ONLINE(x4, tl, p - p0);
    }
    float inv = 1.f / (ssum + 1e-16f);

    // ---- alpha output (att2): parallel from LDS cache ----
    if (WITH_ALPHA) {
        float m_o   = __shfl_xor(m, 32, 64);
        float inv_o = __shfl_xor(inv, 32, 64);
        float m2[2], i2[2];
        m2[h] = m; m2[1 - h] = m_o;
        i2[h] = inv; i2[1 - h] = inv_o;
        int cnt = p1 - p0;
        int ccnt = (cnt < ATT_CAP) ? cnt : ATT_CAP;
        for (int i = l; i < ccnt * 2; i += 64) {
            int idx = i >> 1, hh = i & 1;
            float a = __expf(s_lg[wave][idx][hh] - m2[hh]) * i2[hh];
            alpha_out[plist[p0 + idx] * HEADS + hh] = a;
        }
        // overflow fallback (deg > ATT_CAP): serial recompute (practically never taken)
        for (int pp = p0 + ATT_CAP; pp < p1; pp++) {
            float x4[4], tl;
            ushort4 uv = Q[((size_t)ATT_SRC(pp) << 7) + l];
            ATT_LOGIT(uv, x4, tl);
#pragma unroll
            for (int k = 1; k <= 16; k <<= 1) tl += __shfl_xor(tl, k, 64);
            if ((l & 31) == 0) alpha_out[plist[pp] * HEADS + h] = __expf(tl - m) * inv;
        }
    }

    // ---- epilogue ----
    if (CONCAT) {
        const float* bp = &bias[l << 2];
        ushort4 o;
        o.x = f2bf(fmaxf(acc[0] * inv + bp[0], 0.f));
        o.y = f2bf(fmaxf(acc[1] * inv + bp[1], 0.f));
        o.z = f2bf(fmaxf(acc[2] * inv + bp[2], 0.f));
        o.w = f2bf(fmaxf(acc[3] * inv + bp[3], 0.f));
        ((ushort4*)outp)[((size_t)n << 6) + l] = o;
    } else {
        float o[4];
#pragma unroll
        for (int i = 0; i < 4; i++) {
            float v = acc[i] * inv;
            float other_v = __shfl_xor(v, 32, 64);
            o[i] = 0.5f * (v + other_v);
        }
        if (l < 32) {
            const float* bp = &bias[(l & 31) << 2];
            float4 ov;
            ov.x = fmaxf(o[0] + bp[0], 0.f); ov.y = fmaxf(o[1] + bp[1], 0.f);
            ov.z = fmaxf(o[2] + bp[2], 0.f); ov.w = fmaxf(o[3] + bp[3], 0.f);
            ((float4*)outp)[((size_t)n << 5) + l] = ov;
        }
    }
#undef ATT_SRC
#undef ATT_LOGIT
#undef ATT_ONLINE
}

// ================= pooling over sorted batch_index (node-parallel) =================
template <int C>
__global__ __launch_bounds__(256) void k_pool_atomic(const float* __restrict__ X,
                                                     const int* __restrict__ batch,
                                                     float* __restrict__ pool, int npb) {
    const int RP = 256 / C;
    int c = threadIdx.x & (C - 1);
    int rofs = threadIdx.x / C;
    int i0 = blockIdx.x * npb;
    int i1 = min(i0 + npb, N_NODES);
    float acc = 0.f;
    int gcur = -1;
    for (int i = i0 + rofs; i < i1; i += RP) {
        int g = batch[i];
        if (g != gcur) {
            if (gcur >= 0) atomicAdd(&pool[gcur * C + c], acc);
            acc = 0.f; gcur = g;
        }
        acc += X[(size_t)i * C + c];
    }
    if (gcur >= 0) atomicAdd(&pool[gcur * C + c], acc);
}

// ================= final prediction head =================
__global__ void k_head(const float* __restrict__ pool0, const float* __restrict__ poolL,
                       const float* __restrict__ p0w, const float* __restrict__ p0b,
                       const float* __restrict__ pLw, const float* __restrict__ pLb,
                       const float* __restrict__ ow, const float* __restrict__ ob,
                       float* __restrict__ outputs) {
    int g = blockIdx.x;
    int m = threadIdx.x;
    __shared__ float sh[MIDD];
    if (m < MIDD) {
        float s = p0b[m] + pLb[m];
        for (int k = 0; k < F_INN; k++) s += pool0[g * F_INN + k] * p0w[k * MIDD + m];
        for (int k = 0; k < HID; k++)  s += poolL[g * HID + k] * pLw[k * MIDD + m];
        sh[m] = fmaxf(s, 0.f);
    }
    __syncthreads();
    if (m == 0) {
        float s = ob[0];
        for (int k = 0; k < MIDD; k++) s += sh[k] * ow[k];
        outputs[g] = s;
    }
}

extern "C" void kernel_launch(void* const* d_in, const int* in_sizes, int n_in,
                              void* d_out, int out_size, void* d_ws, size_t ws_size,
                              hipStream_t stream) {
    // ---- inputs ----
    const float* x      = (const float*)d_in[0];
    const int*   ei     = (const int*)d_in[1];
    const int*   aei    = (const int*)d_in[2];
    const int*   batch  = (const int*)d_in[3];
    const float* g0_w1  = (const float*)d_in[4];
    const float* g0_b1  = (const float*)d_in[5];
    const float* g0_bng = (const float*)d_in[6];
    const float* g0_bnb = (const float*)d_in[7];
    const float* g0_w2  = (const float*)d_in[8];
    const float* g0_b2  = (const float*)d_in[9];
    const float* g1_w1  = (const float*)d_in[10];
    const float* g1_b1  = (const float*)d_in[11];
    const float* g1_bng = (const float*)d_in[12];
    const float* g1_bnb = (const float*)d_in[13];
    const float* g1_w2  = (const float*)d_in[14];
    const float* g1_b2  = (const float*)d_in[15];
    const float* bn0_g  = (const float*)d_in[16];
    const float* bn0_b  = (const float*)d_in[17];
    const float* bn1_g  = (const float*)d_in[18];
    const float* bn1_b  = (const float*)d_in[19];
    const float* a1_wl  = (const float*)d_in[20];
    const float* a1_bl  = (const float*)d_in[21];
    const float* a1_wr  = (const float*)d_in[22];
    const float* a1_br  = (const float*)d_in[23];
    const float* a1_att = (const float*)d_in[24];
    const float* a1_bias= (const float*)d_in[25];
    const float* a2_wl  = (const float*)d_in[26];
    const float* a2_bl  = (const float*)d_in[27];
    const float* a2_wr  = (const float*)d_in[28];
    const float* a2_br  = (const float*)d_in[29];
    const float* a2_att = (const float*)d_in[30];
    const float* a2_bias= (const float*)d_in[31];
    const float* p0w    = (const float*)d_in[32];
    const float* p0b    = (const float*)d_in[33];
    const float* pLw    = (const float*)d_in[34];
    const float* pLb    = (const float*)d_in[35];
    const float* ow     = (const float*)d_in[36];
    const float* ob     = (const float*)d_in[37];

    // ---- outputs ----
    float* out_head  = (float*)d_out;
    float* atten_out = out_head + G_GR;
    float* alpha_out = atten_out + (size_t)N_NODES * HID;

    // ---- workspace ----
    float* ws = (float*)d_ws;
    float* sums4 = ws;                                 // 4*256 (s0|s1|s2|s3)
    float* pool0 = sums4 + 4 * 256;                    // G*64
    float* poolL = pool0 + G_GR * F_INN;               // G*128
    int*   btot  = (int*)(poolL + G_GR * HID);         // 3*NBUK (zeroed)
    const size_t zero_bytes = (4 * 256 + G_GR * F_INN + G_GR * HID + 3 * NBUK) * 4;

    int* ip = btot + 3 * NBUK;
    int* bstart = ip; ip += 3 * (NBUK + 1);
    int* bcur   = ip; ip += 3 * NBUK;
    int* rowptr[3]; int* payload[3];
    for (int c = 0; c < 3; c++) {
        rowptr[c]  = ip; ip += N_NODES + 1;
        payload[c] = ip; ip += E_EDGES;
    }
    int2* tmp3 = (int2*)ip; ip += 2 * 3 * E_EDGES;     // [3][E] int2
    const size_t NB = (size_t)N_NODES * HC;
    unsigned short* B1 = (unsigned short*)ip;          // [N,HC] bf16
    unsigned short* B2 = B1 + NB;                      // [N,HC] bf16
    unsigned short* Qb = B2 + NB;                      // [N,512] bf16 merged projections
    unsigned short* g0w1t = Qb + 2 * NB;
    unsigned short* g0w2t = g0w1t + 128 * 64;
    unsigned short* g1w1t = g0w2t + 128 * 128;
    unsigned short* g1w2t = g1w1t + 128 * 128;
    unsigned short* a1wlt = g1w2t + 128 * 128;         // [256,128]
    unsigned short* a1wrt = a1wlt + 256 * 128;         // contiguous -> [512,128]
    unsigned short* a2wlt = a1wrt + 256 * 128;         // [256,256]
    unsigned short* a2wrt = a2wlt + 256 * 256;         // contiguous -> [512,256]

    const int* e_row = ei;
    const int* e_col = ei + E_EDGES;
    const int* a_src = aei;
    const int* a_dst = aei + E_EDGES;

    const int TB = 256;
#define GRID1(n) dim3(CDIV((n), TB))

    // ===== weight transpose+cast =====
    {
        WtJobs jobs;
        jobs.j[0] = {g0_w1, g0w1t, F_INN, HID};
        jobs.j[1] = {g0_w2, g0w2t, HID,   HID};
        jobs.j[2] = {g1_w1, g1w1t, HID,   HID};
        jobs.j[3] = {g1_w2, g1w2t, HID,   HID};
        jobs.j[4] = {a1_wl, a1wlt, HID,   HC};
        jobs.j[5] = {a1_wr, a1wrt, HID,   HC};
        jobs.j[6] = {a2_wl, a2wlt, HC,    HC};
        jobs.j[7] = {a2_wr, a2wrt, HC,    HC};
        k_wt_cast<<<dim3(32, 8), TB, 0, stream>>>(jobs);
    }

    // ===== zero sums/pools/btot in one shot; build 3 CSRs (bucket-granular) =====
    hipMemsetAsync(sums4, 0, zero_bytes, stream);
    {
        Csr3 c;
        c.key[0] = e_row; c.other[0] = e_col;
        c.key[1] = e_col; c.other[1] = e_row;
        c.key[2] = a_dst; c.other[2] = a_src;
        c.btot = btot; c.bstart = bstart; c.bcur = bcur; c.tmp = tmp3;
        for (int i = 0; i < 3; i++) { c.rowptr[i] = rowptr[i]; c.out[i] = payload[i]; }
        k_bhist<<<dim3(CDIV(E_EDGES, 4096), 3), TB, 0, stream>>>(c);
        k_bscan<<<dim3(1), TB, 0, stream>>>(c);
        k_bucketA<<<dim3(CDIV(E_EDGES, 4096), 3), TB, 0, stream>>>(c);
        k_bucketB<<<dim3(NBUK, 3), TB, 0, stream>>>(c);
    }

    const dim3 gemm_g1(1, CDIV(N_NODES, 64));    // N=128, TM=64 (313 blocks)
    const dim3 gemm_gq(4, CDIV(N_NODES, 128));   // N=512, TM=128 (628 blocks)
    const float* NOF = nullptr;

    // ===== GANConv 0 (ping-pong B1/B2 as [N,128]) =====
    k_gather_f32<<<GRID1(N_NODES * 16), TB, 0, stream>>>((const float4*)x, rowptr[0], payload[0], B1);
    k_mfma_gemm<1, 0, 64, 0><<<gemm_g1, TB, 0, stream>>>(B1, g0w1t, g0_b1, NOF, B2, N_NODES, F_INN, HID,
                                                         sums4 + 0, NOF, NOF, NOF);
    k_mfma_gemm<1, 1, 64, 0><<<gemm_g1, TB, 0, stream>>>(B2, g0w2t, g0_b2, NOF, B1, N_NODES, HID, HID,
                                                         sums4 + 256, sums4 + 0, g0_bng, g0_bnb);
    // raw2 (pre-bn0) in B1

    // ===== GANConv 1 =====
    k_gather_bn<<<GRID1(N_NODES * 16), TB, 0, stream>>>((const u16x8*)B1, rowptr[0], payload[0],
                                                        sums4 + 256, bn0_g, bn0_b, (u16x8*)B2);
    k_mfma_gemm<1, 0, 64, 0><<<gemm_g1, TB, 0, stream>>>(B2, g1w1t, g1_b1, NOF, B1, N_NODES, HID, HID,
                                                         sums4 + 512, NOF, NOF, NOF);
    k_mfma_gemm<1, 1, 64, 0><<<gemm_g1, TB, 0, stream>>>(B1, g1w2t, g1_b2, NOF, B2, N_NODES, HID, HID,
                                                         sums4 + 768, sums4 + 512, g1_bng, g1_bnb);
    // raw4 (pre-bn1 = h2 raw) in B2

    // ===== ATTConv 1 (dst=e_col, concat=True): merged wl|wr GEMM -> Q [N,512] =====
    k_mfma_gemm<0, 1, 128, 1><<<gemm_gq, TB, 0, stream>>>(B2, a1wlt, a1_bl, a1_br, Qb, N_NODES, HID, 512,
                                                          nullptr, sums4 + 768, bn1_g, bn1_b);
    k_att_fused<1, 0><<<dim3(N_NODES / 4), TB, 0, stream>>>(
        (const ushort4*)Qb, rowptr[1], payload[1], nullptr, a1_att, a1_bias, (void*)B1, nullptr);
    // emb bf16 in B1 [N,HC]

    // ===== ATTConv 2 (dst=a_dst, concat=False): merged GEMM K=256 -> Q =====
    k_mfma_gemm<0, 0, 128, 1><<<gemm_gq, TB, 0, stream>>>(B1, a2wlt, a2_bl, a2_br, Qb, N_NODES, HC, 512,
                                                          nullptr, NOF, NOF, NOF);
    k_att_fused<0, 1><<<dim3(N_NODES / 4), TB, 0, stream>>>(
        (const ushort4*)Qb, rowptr[2], payload[2], a_src, a2_att, a2_bias, (void*)atten_out, alpha_out);

    // ===== pooling + head =====
    {
        const int npb = 64;  // 313 blocks
        k_pool_atomic<F_INN><<<dim3(CDIV(N_NODES, npb)), TB, 0, stream>>>(x, batch, pool0, npb);
        k_pool_atomic<HID><<<dim3(CDIV(N_NODES, npb)), TB, 0, stream>>>(atten_out, batch, poolL, npb);
    }
    k_head<<<dim3(G_GR), 64, 0, stream>>>(pool0, poolL, p0w, p0b, pLw, pLb, ow, ob, out_head);
}